// Round 1
// baseline (580.727 us; speedup 1.0000x reference)
//
#include <hip/hip_runtime.h>
#include <hip/hip_bf16.h>
#include <math.h>

#define D_MODEL 1024
#define D_HID   4096
#define NE      8
#define NTOK    4096
#define NSLOT   8192

typedef __attribute__((ext_vector_type(8))) short s8v;
typedef __attribute__((ext_vector_type(4))) float f32x4;

__device__ __forceinline__ short f2bf(float f) {
    unsigned u = __float_as_uint(f);
    unsigned r = (u + 0x7fffu + ((u >> 16) & 1u)) >> 16;
    return (short)r;
}

__device__ __forceinline__ void load_lds16(const void* g, void* l) {
    __builtin_amdgcn_global_load_lds(
        (const __attribute__((address_space(1))) void*)g,
        (__attribute__((address_space(3))) void*)l, 16, 0, 0);
}

// ---------------- conversion kernels ----------------

__global__ void k_cvt_x(const float* __restrict__ x, short* __restrict__ xb) {
    int i = blockIdx.x * blockDim.x + threadIdx.x;
    size_t base = (size_t)i * 4;
    float4 v = *(const float4*)(x + base);
    short* o = xb + base;
    o[0] = f2bf(v.x); o[1] = f2bf(v.y); o[2] = f2bf(v.z); o[3] = f2bf(v.w);
}

// in: [E][R][C] fp32 -> out: [E][C][R] bf16
__global__ void k_transpose_cvt(const float* __restrict__ in, short* __restrict__ out,
                                int R, int C) {
    __shared__ float tile[64][65];
    int e = blockIdx.z;
    int c0 = blockIdx.x * 64;
    int r0 = blockIdx.y * 64;
    const float* inp = in + (size_t)e * R * C;
    short* outp = out + (size_t)e * R * C;
    int tx = threadIdx.x & 63;
    int ty = threadIdx.x >> 6;
    #pragma unroll
    for (int rr = ty; rr < 64; rr += 4)
        tile[rr][tx] = inp[(size_t)(r0 + rr) * C + c0 + tx];
    __syncthreads();
    #pragma unroll
    for (int cc = ty; cc < 64; cc += 4)
        outp[(size_t)(c0 + cc) * R + r0 + tx] = f2bf(tile[tx][cc]);
}

// ---------------- router ----------------

__global__ void k_router(const float* __restrict__ x, const float* __restrict__ gw,
                         int* __restrict__ tki, float* __restrict__ tkw) {
    int n = blockIdx.x;
    int lane = threadIdx.x;
    const float* xr = x + (size_t)n * D_MODEL;
    float xs[16];
    #pragma unroll
    for (int j = 0; j < 16; j++) xs[j] = xr[lane + 64 * j];
    float l[8];
    #pragma unroll
    for (int e = 0; e < 8; e++) {
        const float* g = gw + e * D_MODEL;
        float a = 0.f;
        #pragma unroll
        for (int j = 0; j < 16; j++) a += xs[j] * g[lane + 64 * j];
        #pragma unroll
        for (int s = 32; s > 0; s >>= 1) a += __shfl_xor(a, s);
        l[e] = a;
    }
    if (lane == 0) {
        float bv = -1e30f, sv = -1e30f; int bi = 0, si = 0;
        #pragma unroll
        for (int e = 0; e < 8; e++) {
            float v = l[e];
            if (v > bv) { sv = bv; si = bi; bv = v; bi = e; }
            else if (v > sv) { sv = v; si = e; }
        }
        float w0 = 1.f / (1.f + expf(sv - bv));   // = s_top0 / (s_top0+s_top1)
        tki[n * 2] = bi; tki[n * 2 + 1] = si;
        tkw[n * 2] = w0; tkw[n * 2 + 1] = 1.f - w0;
    }
}

// ---------------- bucketing ----------------

__global__ void k_count(const int* __restrict__ tki, int* __restrict__ cnt) {
    int n = blockIdx.x * blockDim.x + threadIdx.x;
    if (n < NTOK) {
        atomicAdd(&cnt[tki[n * 2]], 1);
        atomicAdd(&cnt[tki[n * 2 + 1]], 1);
    }
}

__global__ void k_scan(const int* __restrict__ cnt, int* __restrict__ offs) {
    if (threadIdx.x == 0) {
        int a = 0;
        for (int e = 0; e < NE; e++) { offs[e] = a; a += cnt[e]; }
        offs[NE] = a;
    }
}

__global__ void k_fill(const int* __restrict__ tki, const float* __restrict__ tkw,
                       const int* __restrict__ offs, int* __restrict__ fill,
                       int* __restrict__ list, float* __restrict__ wl,
                       int* __restrict__ slot_of) {
    int n = blockIdx.x * blockDim.x + threadIdx.x;
    if (n < NTOK) {
        #pragma unroll
        for (int k = 0; k < 2; k++) {
            int e = tki[n * 2 + k];
            int p = offs[e] + atomicAdd(&fill[e], 1);
            list[p] = n;
            wl[p] = tkw[n * 2 + k];
            slot_of[n * 2 + k] = p;
        }
    }
}

// ---------------- GEMM 1: h = gelu(X_gather @ W1 + b1), bf16 out ----------------

__global__ __launch_bounds__(256) void k_gemm1(
    const short* __restrict__ xb,      // [NTOK][D_MODEL] bf16
    const short* __restrict__ w1t,     // [E][D_HID][D_MODEL] bf16 (transposed)
    const float* __restrict__ b1,      // [E][D_HID]
    const int* __restrict__ offs,      // [E+1]
    const int* __restrict__ list,      // [NSLOT]
    short* __restrict__ hbuf)          // [NSLOT][D_HID] bf16
{
    int e = blockIdx.z;
    int o0 = offs[e];
    int nE = offs[e + 1] - o0;
    int m0 = blockIdx.y * 128;
    if (m0 >= nE) return;
    int n0 = blockIdx.x * 128;

    __shared__ short As[128 * 64];
    __shared__ short Bs[128 * 64];

    int tid = threadIdx.x;
    int lane = tid & 63;
    int wid = tid >> 6;
    int wm = wid >> 1, wn = wid & 1;

    f32x4 acc[4][4] = {};

    const short* aRow[4];
    const short* bRow[4];
    #pragma unroll
    for (int c = 0; c < 4; c++) {
        int i = c * 256 + tid;
        int rowT = i >> 3, ch = i & 7;
        int r = m0 + rowT; if (r > nE - 1) r = nE - 1;
        int tok = list[o0 + r];
        aRow[c] = xb + (size_t)tok * D_MODEL + ch * 8;
        bRow[c] = w1t + ((size_t)e * D_HID + n0 + rowT) * D_MODEL + ch * 8;
    }

    for (int k0 = 0; k0 < D_MODEL; k0 += 64) {
        __syncthreads();
        #pragma unroll
        for (int c = 0; c < 4; c++) {
            int i = c * 256 + tid;
            load_lds16(aRow[c] + k0, (char*)As + i * 16);
            load_lds16(bRow[c] + k0, (char*)Bs + i * 16);
        }
        asm volatile("s_waitcnt vmcnt(0)" ::: "memory");
        __syncthreads();
        #pragma unroll
        for (int kk = 0; kk < 64; kk += 32) {
            s8v a[4], b[4];
            #pragma unroll
            for (int i = 0; i < 4; i++) {
                a[i] = *(const s8v*)(As + (wm * 64 + i * 16 + (lane & 15)) * 64 + kk + (lane >> 4) * 8);
                b[i] = *(const s8v*)(Bs + (wn * 64 + i * 16 + (lane & 15)) * 64 + kk + (lane >> 4) * 8);
            }
            #pragma unroll
            for (int i = 0; i < 4; i++)
                #pragma unroll
                for (int j = 0; j < 4; j++)
                    acc[i][j] = __builtin_amdgcn_mfma_f32_16x16x32_bf16(a[i], b[j], acc[i][j], 0, 0, 0);
        }
    }

    int rBase = m0 + wm * 64 + (lane >> 4) * 4;
    int cBase = n0 + wn * 64 + (lane & 15);
    #pragma unroll
    for (int i = 0; i < 4; i++) {
        #pragma unroll
        for (int j = 0; j < 4; j++) {
            int cc = cBase + j * 16;
            float bias = b1[e * D_HID + cc];
            #pragma unroll
            for (int rg = 0; rg < 4; rg++) {
                int rr = rBase + i * 16 + rg;
                if (rr < nE) {
                    float v = acc[i][j][rg] + bias;
                    float g = 0.5f * v * (1.0f + erff(v * 0.70710678118f));
                    hbuf[(size_t)(o0 + rr) * D_HID + cc] = f2bf(g);
                }
            }
        }
    }
}

// ---------------- GEMM 2: y = w_slot * (H @ W2 + b2), fp32 out ----------------

__global__ __launch_bounds__(256) void k_gemm2(
    const short* __restrict__ hbuf,    // [NSLOT][D_HID] bf16
    const short* __restrict__ w2t,     // [E][D_MODEL][D_HID] bf16 (transposed)
    const float* __restrict__ b2,      // [E][D_MODEL]
    const int* __restrict__ offs,
    const float* __restrict__ wl,      // [NSLOT]
    float* __restrict__ ybuf)          // [NSLOT][D_MODEL] fp32
{
    int e = blockIdx.z;
    int o0 = offs[e];
    int nE = offs[e + 1] - o0;
    int m0 = blockIdx.y * 128;
    if (m0 >= nE) return;
    int n0 = blockIdx.x * 128;

    __shared__ short As[128 * 64];
    __shared__ short Bs[128 * 64];

    int tid = threadIdx.x;
    int lane = tid & 63;
    int wid = tid >> 6;
    int wm = wid >> 1, wn = wid & 1;

    f32x4 acc[4][4] = {};

    const short* aRow[4];
    const short* bRow[4];
    #pragma unroll
    for (int c = 0; c < 4; c++) {
        int i = c * 256 + tid;
        int rowT = i >> 3, ch = i & 7;
        int r = m0 + rowT; if (r > nE - 1) r = nE - 1;
        aRow[c] = hbuf + (size_t)(o0 + r) * D_HID + ch * 8;
        bRow[c] = w2t + ((size_t)e * D_MODEL + n0 + rowT) * D_HID + ch * 8;
    }

    for (int k0 = 0; k0 < D_HID; k0 += 64) {
        __syncthreads();
        #pragma unroll
        for (int c = 0; c < 4; c++) {
            int i = c * 256 + tid;
            load_lds16(aRow[c] + k0, (char*)As + i * 16);
            load_lds16(bRow[c] + k0, (char*)Bs + i * 16);
        }
        asm volatile("s_waitcnt vmcnt(0)" ::: "memory");
        __syncthreads();
        #pragma unroll
        for (int kk = 0; kk < 64; kk += 32) {
            s8v a[4], b[4];
            #pragma unroll
            for (int i = 0; i < 4; i++) {
                a[i] = *(const s8v*)(As + (wm * 64 + i * 16 + (lane & 15)) * 64 + kk + (lane >> 4) * 8);
                b[i] = *(const s8v*)(Bs + (wn * 64 + i * 16 + (lane & 15)) * 64 + kk + (lane >> 4) * 8);
            }
            #pragma unroll
            for (int i = 0; i < 4; i++)
                #pragma unroll
                for (int j = 0; j < 4; j++)
                    acc[i][j] = __builtin_amdgcn_mfma_f32_16x16x32_bf16(a[i], b[j], acc[i][j], 0, 0, 0);
        }
    }

    int rBase = m0 + wm * 64 + (lane >> 4) * 4;
    int cBase = n0 + wn * 64 + (lane & 15);
    #pragma unroll
    for (int i = 0; i < 4; i++) {
        #pragma unroll
        for (int j = 0; j < 4; j++) {
            int cc = cBase + j * 16;
            float bias = b2[e * D_MODEL + cc];
            #pragma unroll
            for (int rg = 0; rg < 4; rg++) {
                int rr = rBase + i * 16 + rg;
                if (rr < nE) {
                    float w = wl[o0 + rr];
                    ybuf[(size_t)(o0 + rr) * D_MODEL + cc] = w * (acc[i][j][rg] + bias);
                }
            }
        }
    }
}

// ---------------- combine ----------------

__global__ void k_combine(const float* __restrict__ ybuf, const int* __restrict__ slot_of,
                          float* __restrict__ out) {
    int n = blockIdx.x;
    int s0 = slot_of[n * 2], s1 = slot_of[n * 2 + 1];
    int t = threadIdx.x;
    float4 a = *(const float4*)(ybuf + (size_t)s0 * D_MODEL + t * 4);
    float4 b = *(const float4*)(ybuf + (size_t)s1 * D_MODEL + t * 4);
    float4 o;
    o.x = a.x + b.x; o.y = a.y + b.y; o.z = a.z + b.z; o.w = a.w + b.w;
    *(float4*)(out + (size_t)n * D_MODEL + t * 4) = o;
}

// ---------------- launch ----------------

extern "C" void kernel_launch(void* const* d_in, const int* in_sizes, int n_in,
                              void* d_out, int out_size, void* d_ws, size_t ws_size,
                              hipStream_t stream) {
    const float* x  = (const float*)d_in[0];
    const float* gw = (const float*)d_in[1];
    const float* w1 = (const float*)d_in[2];
    const float* b1 = (const float*)d_in[3];
    const float* w2 = (const float*)d_in[4];
    const float* b2 = (const float*)d_in[5];
    float* out = (float*)d_out;

    char* ws = (char*)d_ws;
    size_t off = 0;
    auto alloc = [&](size_t bytes) -> void* {
        void* p = ws + off;
        off += (bytes + 255) & ~(size_t)255;
        return p;
    };
    int*   meta    = (int*)alloc(256);      // cnt[8] | fill[8] | offs[9]
    int*   cnt     = meta;
    int*   fill    = meta + 8;
    int*   offs    = meta + 16;
    int*   tki     = (int*)alloc((size_t)NTOK * 2 * 4);
    float* tkw     = (float*)alloc((size_t)NTOK * 2 * 4);
    int*   list    = (int*)alloc((size_t)NSLOT * 4);
    float* wl      = (float*)alloc((size_t)NSLOT * 4);
    int*   slot_of = (int*)alloc((size_t)NTOK * 2 * 4);
    short* xb      = (short*)alloc((size_t)NTOK * D_MODEL * 2);
    short* w1t     = (short*)alloc((size_t)NE * D_HID * D_MODEL * 2);
    short* w2t     = (short*)alloc((size_t)NE * D_MODEL * D_HID * 2);
    short* hbuf    = (short*)alloc((size_t)NSLOT * D_HID * 2);
    float* ybuf    = (float*)alloc((size_t)NSLOT * D_MODEL * 4);

    hipMemsetAsync(meta, 0, 256, stream);
    k_cvt_x<<<dim3(NTOK * D_MODEL / (4 * 256)), 256, 0, stream>>>(x, xb);
    k_transpose_cvt<<<dim3(D_HID / 64, D_MODEL / 64, NE), 256, 0, stream>>>(w1, w1t, D_MODEL, D_HID);
    k_transpose_cvt<<<dim3(D_MODEL / 64, D_HID / 64, NE), 256, 0, stream>>>(w2, w2t, D_HID, D_MODEL);
    k_router<<<dim3(NTOK), 64, 0, stream>>>(x, gw, tki, tkw);
    k_count<<<dim3(NTOK / 256), 256, 0, stream>>>(tki, cnt);
    k_scan<<<dim3(1), 64, 0, stream>>>(cnt, offs);
    k_fill<<<dim3(NTOK / 256), 256, 0, stream>>>(tki, tkw, offs, fill, list, wl, slot_of);
    k_gemm1<<<dim3(D_HID / 128, 32, NE), 256, 0, stream>>>(xb, w1t, b1, offs, list, hbuf);
    k_gemm2<<<dim3(D_MODEL / 128, 32, NE), 256, 0, stream>>>(hbuf, w2t, b2, offs, wl, ybuf);
    k_combine<<<dim3(NTOK), 256, 0, stream>>>(ybuf, slot_of, out);
}

// Round 3
// 465.726 us; speedup vs baseline: 1.2469x; 1.2469x over previous
//
#include <hip/hip_runtime.h>
#include <hip/hip_bf16.h>
#include <math.h>

#define D_MODEL 1024
#define D_HID   4096
#define NE      8
#define NTOK    4096
#define NSLOT   8192

typedef __attribute__((ext_vector_type(8))) short s8v;
typedef __attribute__((ext_vector_type(4))) float f32x4;

__device__ __forceinline__ short f2bf(float f) {
    unsigned u = __float_as_uint(f);
    unsigned r = (u + 0x7fffu + ((u >> 16) & 1u)) >> 16;
    return (short)r;
}

__device__ __forceinline__ void load_lds16(const short* g, short* l) {
    __builtin_amdgcn_global_load_lds(
        (const __attribute__((address_space(1))) void*)g,
        (__attribute__((address_space(3))) void*)l, 16, 0, 0);
}

// exact-GELU via A&S 7.1.26 erf (|eps| < 1.5e-7), branchless
__device__ __forceinline__ float gelu_f(float v) {
    float z  = v * 0.70710678118f;
    float az = fabsf(z);
    float t  = __builtin_amdgcn_rcpf(fmaf(0.3275911f, az, 1.0f));
    float p  = fmaf(1.061405429f, t, -1.453152027f);
    p = fmaf(p, t, 1.421413741f);
    p = fmaf(p, t, -0.284496736f);
    p = fmaf(p, t, 0.254829592f);
    p = p * t;
    float e  = __expf(-az * az);
    float er = fmaf(-p, e, 1.0f);          // erf(|z|)
    er = copysignf(er, z);
    return v * fmaf(0.5f, er, 0.5f);
}

// ---------------- conversion kernels ----------------

__global__ void k_cvt_x(const float* __restrict__ x, short* __restrict__ xb) {
    int i = blockIdx.x * blockDim.x + threadIdx.x;
    size_t base = (size_t)i * 4;
    float4 v = *(const float4*)(x + base);
    short* o = xb + base;
    o[0] = f2bf(v.x); o[1] = f2bf(v.y); o[2] = f2bf(v.z); o[3] = f2bf(v.w);
}

// in: [E][R][C] fp32 -> out: [E][C][R] bf16
__global__ void k_transpose_cvt(const float* __restrict__ in, short* __restrict__ out,
                                int R, int C) {
    __shared__ float tile[64][65];
    int e = blockIdx.z;
    int c0 = blockIdx.x * 64;
    int r0 = blockIdx.y * 64;
    const float* inp = in + (size_t)e * R * C;
    short* outp = out + (size_t)e * R * C;
    int tx = threadIdx.x & 63;
    int ty = threadIdx.x >> 6;
    #pragma unroll
    for (int rr = ty; rr < 64; rr += 4)
        tile[rr][tx] = inp[(size_t)(r0 + rr) * C + c0 + tx];
    __syncthreads();
    #pragma unroll
    for (int cc = ty; cc < 64; cc += 4)
        outp[(size_t)(c0 + cc) * R + r0 + tx] = f2bf(tile[tx][cc]);
}

// ---------------- router ----------------

__global__ void k_router(const float* __restrict__ x, const float* __restrict__ gw,
                         int* __restrict__ tki, float* __restrict__ tkw) {
    int n = blockIdx.x;
    int lane = threadIdx.x;
    const float* xr = x + (size_t)n * D_MODEL;
    float xs[16];
    #pragma unroll
    for (int j = 0; j < 16; j++) xs[j] = xr[lane + 64 * j];
    float l[8];
    #pragma unroll
    for (int e = 0; e < 8; e++) {
        const float* g = gw + e * D_MODEL;
        float a = 0.f;
        #pragma unroll
        for (int j = 0; j < 16; j++) a += xs[j] * g[lane + 64 * j];
        #pragma unroll
        for (int s = 32; s > 0; s >>= 1) a += __shfl_xor(a, s);
        l[e] = a;
    }
    if (lane == 0) {
        float bv = -1e30f, sv = -1e30f; int bi = 0, si = 0;
        #pragma unroll
        for (int e = 0; e < 8; e++) {
            float v = l[e];
            if (v > bv) { sv = bv; si = bi; bv = v; bi = e; }
            else if (v > sv) { sv = v; si = e; }
        }
        float w0 = 1.f / (1.f + expf(sv - bv));
        tki[n * 2] = bi; tki[n * 2 + 1] = si;
        tkw[n * 2] = w0; tkw[n * 2 + 1] = 1.f - w0;
    }
}

// ---------------- bucketing ----------------

__global__ void k_count(const int* __restrict__ tki, int* __restrict__ cnt) {
    int n = blockIdx.x * blockDim.x + threadIdx.x;
    if (n < NTOK) {
        atomicAdd(&cnt[tki[n * 2]], 1);
        atomicAdd(&cnt[tki[n * 2 + 1]], 1);
    }
}

__global__ void k_scan(const int* __restrict__ cnt, int* __restrict__ offs) {
    if (threadIdx.x == 0) {
        int a = 0;
        for (int e = 0; e < NE; e++) { offs[e] = a; a += cnt[e]; }
        offs[NE] = a;
    }
}

__global__ void k_fill(const int* __restrict__ tki, const float* __restrict__ tkw,
                       const int* __restrict__ offs, int* __restrict__ fill,
                       int* __restrict__ list, float* __restrict__ wl,
                       int* __restrict__ slot_of) {
    int n = blockIdx.x * blockDim.x + threadIdx.x;
    if (n < NTOK) {
        #pragma unroll
        for (int k = 0; k < 2; k++) {
            int e = tki[n * 2 + k];
            int p = offs[e] + atomicAdd(&fill[e], 1);
            list[p] = n;
            wl[p] = tkw[n * 2 + k];
            slot_of[n * 2 + k] = p;
        }
    }
}

// ---------------- GEMM 1: h = gelu(X_gather @ W1 + b1), bf16 out ----------------
// LDS tile [128 rows][64 k] bf16. XOR swizzle: physical 16B slot s of row r
// holds logical chunk s^(r&7). Staged with linear LDS dest (global_load_lds
// requirement) + pre-swizzled per-lane global source; ds_read applies same XOR.

__global__ __launch_bounds__(256) void k_gemm1(
    const short* __restrict__ xb,      // [NTOK][D_MODEL] bf16
    const short* __restrict__ w1t,     // [E][D_HID][D_MODEL] bf16 (transposed)
    const float* __restrict__ b1,      // [E][D_HID]
    const int* __restrict__ offs,
    const int* __restrict__ list,
    short* __restrict__ hbuf)          // [NSLOT][D_HID] bf16
{
    int e = blockIdx.z;
    int o0 = offs[e];
    int nE = offs[e + 1] - o0;
    int m0 = blockIdx.y * 128;
    if (m0 >= nE) return;
    int n0 = blockIdx.x * 128;

    __shared__ short As[128 * 64];
    __shared__ short Bs[128 * 64];

    int tid = threadIdx.x;
    int lane = tid & 63;
    int wid = tid >> 6;
    int wm = wid >> 1, wn = wid & 1;

    f32x4 acc[4][4] = {};

    const short* aS[4]; const short* bS[4];
    short* aD[4]; short* bD[4];
    #pragma unroll
    for (int c = 0; c < 4; c++) {
        int i = c * 256 + tid;
        int rowT = i >> 3, s = i & 7;
        int ch = s ^ (rowT & 7);                 // pre-swizzled source chunk
        int r = m0 + rowT; if (r > nE - 1) r = nE - 1;
        int tok = list[o0 + r];
        aS[c] = xb + (size_t)tok * D_MODEL + ch * 8;
        bS[c] = w1t + ((size_t)e * D_HID + n0 + rowT) * D_MODEL + ch * 8;
        aD[c] = As + i * 8;                      // linear LDS dest
        bD[c] = Bs + i * 8;
    }

    int aO[4][2], bO[4][2];
    #pragma unroll
    for (int i = 0; i < 4; i++)
        #pragma unroll
        for (int k = 0; k < 2; k++) {
            int l = k * 4 + (lane >> 4);
            int R = wm * 64 + i * 16 + (lane & 15);
            aO[i][k] = R * 64 + ((l ^ (R & 7)) * 8);
            R = wn * 64 + i * 16 + (lane & 15);
            bO[i][k] = R * 64 + ((l ^ (R & 7)) * 8);
        }

    for (int k0 = 0; k0 < D_MODEL; k0 += 64) {
        __syncthreads();
        #pragma unroll
        for (int c = 0; c < 4; c++) {
            load_lds16(aS[c] + k0, aD[c]);
            load_lds16(bS[c] + k0, bD[c]);
        }
        asm volatile("s_waitcnt vmcnt(0)" ::: "memory");
        __syncthreads();
        #pragma unroll
        for (int kk2 = 0; kk2 < 2; kk2++) {
            s8v a[4], b[4];
            #pragma unroll
            for (int i = 0; i < 4; i++) {
                a[i] = *(const s8v*)(As + aO[i][kk2]);
                b[i] = *(const s8v*)(Bs + bO[i][kk2]);
            }
            #pragma unroll
            for (int i = 0; i < 4; i++)
                #pragma unroll
                for (int j = 0; j < 4; j++)
                    acc[i][j] = __builtin_amdgcn_mfma_f32_16x16x32_bf16(a[i], b[j], acc[i][j], 0, 0, 0);
        }
    }

    int rBase = m0 + wm * 64 + (lane >> 4) * 4;
    int cBase = n0 + wn * 64 + (lane & 15);
    #pragma unroll
    for (int i = 0; i < 4; i++) {
        #pragma unroll
        for (int j = 0; j < 4; j++) {
            int cc = cBase + j * 16;
            float bias = b1[e * D_HID + cc];
            #pragma unroll
            for (int rg = 0; rg < 4; rg++) {
                int rr = rBase + i * 16 + rg;
                if (rr < nE) {
                    float v = acc[i][j][rg] + bias;
                    hbuf[(size_t)(o0 + rr) * D_HID + cc] = f2bf(gelu_f(v));
                }
            }
        }
    }
}

// ---------------- GEMM 2: y = w_slot * (H @ W2 + b2), fp32 out ----------------

__global__ __launch_bounds__(256) void k_gemm2(
    const short* __restrict__ hbuf,    // [NSLOT][D_HID] bf16
    const short* __restrict__ w2t,     // [E][D_MODEL][D_HID] bf16 (transposed)
    const float* __restrict__ b2,
    const int* __restrict__ offs,
    const float* __restrict__ wl,
    float* __restrict__ ybuf)          // [NSLOT][D_MODEL] fp32
{
    int e = blockIdx.z;
    int o0 = offs[e];
    int nE = offs[e + 1] - o0;
    int m0 = blockIdx.y * 128;
    if (m0 >= nE) return;
    int n0 = blockIdx.x * 128;

    __shared__ short As[128 * 64];
    __shared__ short Bs[128 * 64];

    int tid = threadIdx.x;
    int lane = tid & 63;
    int wid = tid >> 6;
    int wm = wid >> 1, wn = wid & 1;

    f32x4 acc[4][4] = {};

    const short* aS[4]; const short* bS[4];
    short* aD[4]; short* bD[4];
    #pragma unroll
    for (int c = 0; c < 4; c++) {
        int i = c * 256 + tid;
        int rowT = i >> 3, s = i & 7;
        int ch = s ^ (rowT & 7);
        int r = m0 + rowT; if (r > nE - 1) r = nE - 1;
        aS[c] = hbuf + (size_t)(o0 + r) * D_HID + ch * 8;
        bS[c] = w2t + ((size_t)e * D_MODEL + n0 + rowT) * D_HID + ch * 8;
        aD[c] = As + i * 8;
        bD[c] = Bs + i * 8;
    }

    int aO[4][2], bO[4][2];
    #pragma unroll
    for (int i = 0; i < 4; i++)
        #pragma unroll
        for (int k = 0; k < 2; k++) {
            int l = k * 4 + (lane >> 4);
            int R = wm * 64 + i * 16 + (lane & 15);
            aO[i][k] = R * 64 + ((l ^ (R & 7)) * 8);
            R = wn * 64 + i * 16 + (lane & 15);
            bO[i][k] = R * 64 + ((l ^ (R & 7)) * 8);
        }

    for (int k0 = 0; k0 < D_HID; k0 += 64) {
        __syncthreads();
        #pragma unroll
        for (int c = 0; c < 4; c++) {
            load_lds16(aS[c] + k0, aD[c]);
            load_lds16(bS[c] + k0, bD[c]);
        }
        asm volatile("s_waitcnt vmcnt(0)" ::: "memory");
        __syncthreads();
        #pragma unroll
        for (int kk2 = 0; kk2 < 2; kk2++) {
            s8v a[4], b[4];
            #pragma unroll
            for (int i = 0; i < 4; i++) {
                a[i] = *(const s8v*)(As + aO[i][kk2]);
                b[i] = *(const s8v*)(Bs + bO[i][kk2]);
            }
            #pragma unroll
            for (int i = 0; i < 4; i++)
                #pragma unroll
                for (int j = 0; j < 4; j++)
                    acc[i][j] = __builtin_amdgcn_mfma_f32_16x16x32_bf16(a[i], b[j], acc[i][j], 0, 0, 0);
        }
    }

    int rBase = m0 + wm * 64 + (lane >> 4) * 4;
    int cBase = n0 + wn * 64 + (lane & 15);
    #pragma unroll
    for (int i = 0; i < 4; i++) {
        #pragma unroll
        for (int j = 0; j < 4; j++) {
            int cc = cBase + j * 16;
            float bias = b2[e * D_MODEL + cc];
            #pragma unroll
            for (int rg = 0; rg < 4; rg++) {
                int rr = rBase + i * 16 + rg;
                if (rr < nE) {
                    float w = wl[o0 + rr];
                    ybuf[(size_t)(o0 + rr) * D_MODEL + cc] = w * (acc[i][j][rg] + bias);
                }
            }
        }
    }
}

// ---------------- combine ----------------

__global__ void k_combine(const float* __restrict__ ybuf, const int* __restrict__ slot_of,
                          float* __restrict__ out) {
    int n = blockIdx.x;
    int s0 = slot_of[n * 2], s1 = slot_of[n * 2 + 1];
    int t = threadIdx.x;
    float4 a = *(const float4*)(ybuf + (size_t)s0 * D_MODEL + t * 4);
    float4 b = *(const float4*)(ybuf + (size_t)s1 * D_MODEL + t * 4);
    float4 o;
    o.x = a.x + b.x; o.y = a.y + b.y; o.z = a.z + b.z; o.w = a.w + b.w;
    *(float4*)(out + (size_t)n * D_MODEL + t * 4) = o;
}

// ---------------- launch ----------------

extern "C" void kernel_launch(void* const* d_in, const int* in_sizes, int n_in,
                              void* d_out, int out_size, void* d_ws, size_t ws_size,
                              hipStream_t stream) {
    const float* x  = (const float*)d_in[0];
    const float* gw = (const float*)d_in[1];
    const float* w1 = (const float*)d_in[2];
    const float* b1 = (const float*)d_in[3];
    const float* w2 = (const float*)d_in[4];
    const float* b2 = (const float*)d_in[5];
    float* out = (float*)d_out;

    char* ws = (char*)d_ws;
    size_t off = 0;
    auto alloc = [&](size_t bytes) -> void* {
        void* p = ws + off;
        off += (bytes + 255) & ~(size_t)255;
        return p;
    };
    int*   meta    = (int*)alloc(256);
    int*   cnt     = meta;
    int*   fill    = meta + 8;
    int*   offs    = meta + 16;
    int*   tki     = (int*)alloc((size_t)NTOK * 2 * 4);
    float* tkw     = (float*)alloc((size_t)NTOK * 2 * 4);
    int*   list    = (int*)alloc((size_t)NSLOT * 4);
    float* wl      = (float*)alloc((size_t)NSLOT * 4);
    int*   slot_of = (int*)alloc((size_t)NTOK * 2 * 4);
    short* xb      = (short*)alloc((size_t)NTOK * D_MODEL * 2);
    short* w1t     = (short*)alloc((size_t)NE * D_HID * D_MODEL * 2);
    short* w2t     = (short*)alloc((size_t)NE * D_MODEL * D_HID * 2);
    short* hbuf    = (short*)alloc((size_t)NSLOT * D_HID * 2);
    float* ybuf    = (float*)alloc((size_t)NSLOT * D_MODEL * 4);

    hipMemsetAsync(meta, 0, 256, stream);
    k_cvt_x<<<dim3(NTOK * D_MODEL / (4 * 256)), 256, 0, stream>>>(x, xb);
    k_transpose_cvt<<<dim3(D_HID / 64, D_MODEL / 64, NE), 256, 0, stream>>>(w1, w1t, D_MODEL, D_HID);
    k_transpose_cvt<<<dim3(D_MODEL / 64, D_HID / 64, NE), 256, 0, stream>>>(w2, w2t, D_HID, D_MODEL);
    k_router<<<dim3(NTOK), 64, 0, stream>>>(x, gw, tki, tkw);
    k_count<<<dim3(NTOK / 256), 256, 0, stream>>>(tki, cnt);
    k_scan<<<dim3(1), 64, 0, stream>>>(cnt, offs);
    k_fill<<<dim3(NTOK / 256), 256, 0, stream>>>(tki, tkw, offs, fill, list, wl, slot_of);
    k_gemm1<<<dim3(D_HID / 128, 32, NE), 256, 0, stream>>>(xb, w1t, b1, offs, list, hbuf);
    k_gemm2<<<dim3(D_MODEL / 128, 32, NE), 256, 0, stream>>>(hbuf, w2t, b2, offs, wl, ybuf);
    k_combine<<<dim3(NTOK), 256, 0, stream>>>(ybuf, slot_of, out);
}